// Round 10
// baseline (2780.755 us; speedup 1.0000x reference)
//
#include <hip/hip_runtime.h>
#include <stdint.h>

// DCRNN forward, MI355X — persistent plain-launch, L2-coherent state exchange.
//  R10 = R9 + fix: zero Hbuf buf0 pad cols [F,FP) in the identity build.
//  (R9's NaN: MODE-2's fp32 overlay leaves NaN-capable bf16 bit patterns in
//   buf0 cols >= F; proj(0) reads them and NaN*0-weight = NaN. xsT stale pads
//   remain safe: only finite bf16 ever written there.)
//  - Stage protocol: [build Hbuf id from regs; zero pads; proj(0)] overlapped
//    with barrier; WAIT; stage xsT (16B sc0 loads, same-XCD L2-served);
//    4x {hop GEMM; proj} double-buffered; fused GRU epilogue; ARRIVE.
//  - main: 256 blocks x 512 threads = 64 batches x 4 row-quadrants; 102400 B LDS
//    forces 1 block/CU -> all 256 blocks co-resident. Per-batch 4-block barrier
//    (relaxed agent atomics; batch's blocks share blockIdx%8 -> same XCD L2).
//  - State writes: 8B agent-scope atomic stores (write-through, L2-coherent).

typedef short short8 __attribute__((ext_vector_type(8)));
typedef float f32x4 __attribute__((ext_vector_type(4)));
typedef unsigned short ushort4v __attribute__((ext_vector_type(4)));
typedef unsigned long long u64;
typedef int i32x4 __attribute__((ext_vector_type(4)));

#define DEVI __device__ __forceinline__

DEVI unsigned short f2bf(float x) {
  unsigned int u = __builtin_bit_cast(unsigned int, x);
  u += 0x7FFFu + ((u >> 16) & 1u);  // RNE
  return (unsigned short)(u >> 16);
}
DEVI void ast(u64* p, u64 v) { __hip_atomic_store(p, v, __ATOMIC_RELAXED, __HIP_MEMORY_SCOPE_AGENT); }
DEVI float aldf(const float* p) { return __hip_atomic_load(p, __ATOMIC_RELAXED, __HIP_MEMORY_SCOPE_AGENT); }
DEVI void astf(float* p, float v) { __hip_atomic_store(p, v, __ATOMIC_RELAXED, __HIP_MEMORY_SCOPE_AGENT); }

// 16B load, L1-bypass (sc0), L2-served: same-XCD coherent with sc1 write-through stores.
DEVI i32x4 ldg_sc0(const void* p) {
  i32x4 r;
  asm volatile("global_load_dwordx4 %0, %1, off sc0" : "=v"(r) : "v"(p));
  return r;
}

struct KP {
  const float* enc_in;
  const float* sup0; const float* sup1;
  const float* Wsrc[8];
  const float* bias[8];
  const float* prW; const float* prB;
  float* out;
  unsigned short* A;        // [4][256][256] bf16
  unsigned short* Wp[8];    // packed [O][5*FP] bf16
  unsigned short* H0[2];    // [64 b][64 f][256 n] bf16 rows, ping-pong
  unsigned short* H1[2];
  unsigned short* RH0;      // r*h rows
  unsigned short* RH1;
  float* XD;                // [64][256] decoder feedback
  unsigned* ctr;            // 64 per-batch counters, 256B apart
};

// ---------------- prep kernel (512 blocks x 256) ----------------
__global__ void prep(KP p) {
  const int i = blockIdx.x, tid = threadIdx.x;
  {  // A matrices
    const int s = i & 1, r = i >> 1;
    const float* S = s ? p.sup1 : p.sup0;
    float acc = 0.f;
    for (int k = 0; k < 256; ++k) acc = fmaf(S[r * 256 + k], S[k * 256 + tid], acc);
    p.A[(2 * s + 0) * 65536 + r * 256 + tid] = f2bf(S[r * 256 + tid]);
    p.A[(2 * s + 1) * 65536 + r * 256 + tid] = f2bf(2.f * acc - (r == tid ? 1.f : 0.f));
  }
  {  // packed weights: Wp[o][m*FP+f] = W[f,m,o], f zero-padded to FP
    const int gtid = i * 256 + tid;
    const int Fs[8]  = {66, 66, 128, 128, 65, 65, 128, 128};
    const int Os[8]  = {128, 64, 128, 64, 128, 64, 128, 64};
    const int FPs[8] = {96, 96, 128, 128, 96, 96, 128, 128};
    for (int w = 0; w < 8; ++w) {
      const int FPw = FPs[w], KPw = 5 * FPw, tot = Os[w] * KPw;
      for (int e = gtid; e < tot; e += 512 * 256) {
        const int o = e / KPw, k2 = e - o * KPw, m = k2 / FPw, f = k2 - m * FPw;
        p.Wp[w][e] = f2bf((f < Fs[w]) ? p.Wsrc[w][(f * 5 + m) * Os[w] + o] : 0.f);
      }
    }
  }
  {  // zero initial hidden via agent-scope stores
    const int gtid = i * 256 + tid;
    u64* z0 = (u64*)p.H0[0];
    u64* z1 = (u64*)p.H1[0];
    ast(z0 + 2 * gtid, 0); ast(z0 + 2 * gtid + 1, 0);
    ast(z1 + 2 * gtid, 0); ast(z1 + 2 * gtid + 1, 0);
  }
  if (i == 0 && tid < 64)
    __hip_atomic_store(p.ctr + tid * 64, 0u, __ATOMIC_RELAXED, __HIP_MEMORY_SCOPE_AGENT);
}

// ---------------- fused diffusion-conv stage ----------------
// MODE 0: gates (O=128, sigmoid; rh -> regs + RH rows, u regs)
// MODE 1: cand  (O=64, tanh; GRU update of hreg; writes H rows)
// MODE 2: MODE1 + final projection (writes out slice and XD)
template<int IND, int FP, int MODE>
DEVI void dc_stage(int b, int n0, int tid,
                   const float* xf32,             // IND==2: enc x base; IND==1: XD base (or null)
                   const unsigned short* xbf,     // IND==64: global x rows (layer-0 H)
                   const unsigned short* hrows,   // global h-or-rh rows [64 f][256 n]
                   f32x4 (&idh)[2], f32x4 (&idx)[2],  // identity regs: h-part, x-part(IND==64)
                   f32x4 (&hreg)[2], f32x4 (&ureg)[2], f32x4 (&rhreg)[2],
                   const unsigned short* Amats,
                   const unsigned short* Wp, const float* bias,
                   unsigned short* grows,         // output rows (RH or Hnew)
                   const float* projW, const float* projB,
                   float* outp, float* xdout,
                   unsigned short* xsT, unsigned short* Hbuf,
                   unsigned* ctr, unsigned& st)
{
  constexpr int F = IND + 64;
  constexpr int O = (MODE == 0) ? 128 : 64;
  constexpr int KPW = 5 * FP;
  constexpr int XS = 264;            // xsT row stride (bf16 elems)
  constexpr int HS = 136;            // Hbuf row stride
  constexpr int HB = 64 * HS;        // one Hbuf buffer
  constexpr int NFT = FP / 16;
  constexpr int NOT_ = O / 16;
  constexpr int FT_W = (NFT + 3) / 4;
  constexpr int OT_W = (NOT_ + 3) / 4;

  const int wv8 = tid >> 6, ln = tid & 63;
  const int l15 = ln & 15, l4 = ln >> 4;
  const int wr = wv8 & 1, wc = wv8 >> 1;   // row-half / tile-column quarter
  const int r0 = wr * 32;

  // ---- 1. Hbuf buf0 identity slice from registers (pre-barrier overlap) ----
#pragma unroll
  for (int rt = 0; rt < 2; ++rt)
#pragma unroll
    for (int j = 0; j < 4; ++j) {
      const int nl = r0 + rt * 16 + l4 * 4 + j;
      Hbuf[nl * HS + IND + wc * 16 + l15] = f2bf(idh[rt][j]);
      if (IND == 64) Hbuf[nl * HS + wc * 16 + l15] = f2bf(idx[rt][j]);
    }
  if (IND == 2) {
    if (tid < 128)
      Hbuf[(tid >> 1) * HS + (tid & 1)] = f2bf(xf32[(n0 + (tid >> 1)) * 2 + (tid & 1)]);
  } else if (IND == 1) {
    if (tid < 64)
      Hbuf[tid * HS] = xf32 ? f2bf(aldf(xf32 + n0 + tid)) : (unsigned short)0;
  }
  if (F < FP) {   // R10 FIX: clear buf0 pad cols — MODE-2's fp32 overlay leaves
                  // NaN-capable bf16 bit patterns there, and NaN*0(Wp pad) = NaN.
    for (int e = tid; e < (FP - F) * 64; e += 512) {
      const int f = F + (e >> 6), nl = e & 63;
      Hbuf[nl * HS + f] = 0;
    }
  }
  __syncthreads();

  f32x4 pacc[2][OT_W];
#pragma unroll
  for (int rt = 0; rt < 2; ++rt)
#pragma unroll
    for (int oi = 0; oi < OT_W; ++oi) pacc[rt][oi] = 0.f;

  auto proj_step = [&](int m, const unsigned short* hb) {
#pragma unroll
    for (int k0 = 0; k0 < FP; k0 += 32) {
      short8 af[2];
#pragma unroll
      for (int rt = 0; rt < 2; ++rt)
        af[rt] = *reinterpret_cast<const short8*>(&hb[(r0 + rt * 16 + l15) * HS + k0 + l4 * 8]);
#pragma unroll
      for (int oi = 0; oi < OT_W; ++oi) {
        const int ot = wc + 4 * oi;
        if (ot < NOT_) {
          short8 bf = *reinterpret_cast<const short8*>(&Wp[(ot * 16 + l15) * KPW + m * FP + k0 + l4 * 8]);
#pragma unroll
          for (int rt = 0; rt < 2; ++rt)
            pacc[rt][oi] = __builtin_amdgcn_mfma_f32_16x16x32_bf16(af[rt], bf, pacc[rt][oi], 0, 0, 0);
        }
      }
    }
  };

  proj_step(0, Hbuf);  // identity slice (buf0), overlapped with barrier wait

  // ---- 2. WAIT: all blocks' previous-stage state visible ----
  if (tid == 0) {
    const unsigned target = st * 4u;
    while (__hip_atomic_load(ctr, __ATOMIC_RELAXED, __HIP_MEMORY_SCOPE_AGENT) < target)
      __builtin_amdgcn_s_sleep(2);
  }
  __syncthreads();

  // ---- 3. stage xsT [f][n]: 16B sc0 loads (L2-served, all in flight) ----
  {
    i32x4 va[4];
#pragma unroll
    for (int it = 0; it < 4; ++it)
      va[it] = ldg_sc0(reinterpret_cast<const char*>(hrows) + (tid + it * 512) * 16);
    i32x4 vb[4];
    if (IND == 64) {
#pragma unroll
      for (int it = 0; it < 4; ++it)
        vb[it] = ldg_sc0(reinterpret_cast<const char*>(xbf) + (tid + it * 512) * 16);
    }
    asm volatile("s_waitcnt vmcnt(0)" ::: "memory");
#pragma unroll
    for (int it = 0; it < 4; ++it) {
      const int g = tid + it * 512, row = g >> 5, c = g & 31;
      *reinterpret_cast<i32x4*>(&xsT[(IND + row) * XS + c * 8]) = va[it];
    }
    if (IND == 64) {
#pragma unroll
      for (int it = 0; it < 4; ++it) {
        const int g = tid + it * 512, row = g >> 5, c = g & 31;
        *reinterpret_cast<i32x4*>(&xsT[row * XS + c * 8]) = vb[it];
      }
    }
    if (IND == 2) {
      xsT[(tid & 1) * XS + (tid >> 1)] = f2bf(xf32[tid]);
    } else if (IND == 1) {
      if (tid < 256) xsT[tid] = xf32 ? f2bf(aldf(xf32 + tid)) : (unsigned short)0;
    }
    // xsT pad rows [F,FP): stale but always finite bf16 (only bf16 data is ever
    // written to xsT) -> hop-of-stale x Wp-zero = 0. No re-zeroing needed.
  }
  __syncthreads();

  // ---- 4. hops + projection (Hbuf double-buffered) ----
  for (int mi = 0; mi < 4; ++mi) {
    const unsigned short* Am = Amats + mi * 65536;
    f32x4 hacc[2][FT_W];
#pragma unroll
    for (int rt = 0; rt < 2; ++rt)
#pragma unroll
      for (int fi = 0; fi < FT_W; ++fi) hacc[rt][fi] = 0.f;

#pragma unroll
    for (int k0 = 0; k0 < 256; k0 += 32) {
      short8 af[2];
#pragma unroll
      for (int rt = 0; rt < 2; ++rt)
        af[rt] = *reinterpret_cast<const short8*>(&Am[(n0 + r0 + rt * 16 + l15) * 256 + k0 + l4 * 8]);
#pragma unroll
      for (int fi = 0; fi < FT_W; ++fi) {
        const int ft = wc + 4 * fi;
        if (ft < NFT) {
          short8 bf = *reinterpret_cast<const short8*>(&xsT[(ft * 16 + l15) * XS + k0 + l4 * 8]);
#pragma unroll
          for (int rt = 0; rt < 2; ++rt)
            hacc[rt][fi] = __builtin_amdgcn_mfma_f32_16x16x32_bf16(af[rt], bf, hacc[rt][fi], 0, 0, 0);
        }
      }
    }
    unsigned short* dst = Hbuf + ((mi + 1) & 1) * HB;   // disjoint from proj(mi)'s buffer
#pragma unroll
    for (int fi = 0; fi < FT_W; ++fi) {
      const int ft = wc + 4 * fi;
      if (ft < NFT) {
#pragma unroll
        for (int rt = 0; rt < 2; ++rt)
#pragma unroll
          for (int j = 0; j < 4; ++j)
            dst[(r0 + rt * 16 + l4 * 4 + j) * HS + ft * 16 + l15] = f2bf(hacc[rt][fi][j]);
      }
    }
    __syncthreads();
    proj_step(mi + 1, dst);
  }

  // ---- 5. epilogue ----
  if (MODE == 0) {
    const float br = bias[wc * 16 + l15];
    const float bu = bias[64 + wc * 16 + l15];
#pragma unroll
    for (int rt = 0; rt < 2; ++rt) {
      ushort4v pk;
#pragma unroll
      for (int jj = 0; jj < 4; ++jj) {
        const float r = 1.f / (1.f + __expf(-(pacc[rt][0][jj] + br)));
        ureg[rt][jj] = 1.f / (1.f + __expf(-(pacc[rt][1][jj] + bu)));
        rhreg[rt][jj] = r * hreg[rt][jj];
        pk[jj] = f2bf(rhreg[rt][jj]);
      }
      ast((u64*)(grows + (wc * 16 + l15) * 256 + n0 + r0 + rt * 16 + l4 * 4),
          __builtin_bit_cast(u64, pk));
    }
  } else {
    float* hrow = reinterpret_cast<float*>(Hbuf);   // [64][68] fp32 overlay of buf0
    if (MODE == 2) __syncthreads();                 // proj(4) readers (buf0) done
    const float bc = bias[wc * 16 + l15];
#pragma unroll
    for (int rt = 0; rt < 2; ++rt) {
      f32x4 hn;
      ushort4v pk;
#pragma unroll
      for (int jj = 0; jj < 4; ++jj) {
        const float ex = __expf(2.f * (pacc[rt][0][jj] + bc));
        const float c = 1.f - 2.f / (ex + 1.f);     // tanh
        hn[jj] = ureg[rt][jj] * hreg[rt][jj] + (1.f - ureg[rt][jj]) * c;
        pk[jj] = f2bf(hn[jj]);
      }
      hreg[rt] = hn;
      ast((u64*)(grows + (wc * 16 + l15) * 256 + n0 + r0 + rt * 16 + l4 * 4),
          __builtin_bit_cast(u64, pk));
      if (MODE == 2) {
#pragma unroll
        for (int jj = 0; jj < 4; ++jj)
          hrow[(r0 + rt * 16 + l4 * 4 + jj) * 68 + wc * 16 + l15] = hn[jj];
      }
    }
    if (MODE == 2) {
      __syncthreads();
      if (tid < 64) {
        float acc = projB[0];
        const float* hr = hrow + tid * 68;
#pragma unroll
        for (int hid = 0; hid < 64; ++hid) acc = fmaf(hr[hid], projW[hid], acc);
        outp[b * 3072 + n0 + tid] = acc;            // host-read output
        astf(xdout + b * 256 + n0 + tid, acc);      // cross-block feedback
      }
    }
  }

  // ---- 6. ARRIVE: my stores visible, signal ----
  asm volatile("s_waitcnt vmcnt(0)" ::: "memory");
  __syncthreads();
  if (tid == 0) __hip_atomic_fetch_add(ctr, 1u, __ATOMIC_RELAXED, __HIP_MEMORY_SCOPE_AGENT);
  ++st;
}

// ---------------- persistent main kernel (256 blocks x 512) ----------------
__launch_bounds__(512, 2)
__global__ void dcrnn_main(KP p) {
  __shared__ __align__(16) unsigned short xsT[128 * 264];     // 67584 B
  __shared__ __align__(16) unsigned short Hbuf[2 * 64 * 136]; // 34816 B -> 102400, 1 blk/CU
  const int tid = threadIdx.x;
  const int i = (int)blockIdx.x;
  const int q = (i >> 3) & 3;
  const int b = (i & 7) + 8 * (i >> 5);   // batch's 4 blocks share blockIdx%8 (same XCD)
  const int n0 = q * 64;

  // one-time LDS zero (pads + stale protection for first stage)
  for (int e = tid; e < 128 * 264; e += 512) xsT[e] = 0;
  for (int e = tid; e < 2 * 64 * 136; e += 512) Hbuf[e] = 0;

  unsigned* ctr = p.ctr + b * 64;
  unsigned st = 0;

  // prologue ARRIVE (counts as stage-0 arrival; prep's state already visible)
  __syncthreads();
  if (tid == 0) __hip_atomic_fetch_add(ctr, 1u, __ATOMIC_RELAXED, __HIP_MEMORY_SCOPE_AGENT);
  ++st;

  f32x4 h0[2], h1[2], u[2], rh[2];
#pragma unroll
  for (int rt = 0; rt < 2; ++rt) { h0[rt] = 0.f; h1[rt] = 0.f; u[rt] = 0.f; rh[rt] = 0.f; }
  int c0 = 0, c1 = 0;

  // ---- encoder ----
  for (int t = 0; t < 12; ++t) {
    const float* x0 = p.enc_in + (b * 12 + t) * 512;
    dc_stage<2, 96, 0>(b, n0, tid, x0, nullptr, p.H0[c0] + b * 16384,
                       h0, h0, h0, u, rh, p.A, p.Wp[0], p.bias[0],
                       p.RH0 + b * 16384, nullptr, nullptr, nullptr, nullptr,
                       xsT, Hbuf, ctr, st);
    dc_stage<2, 96, 1>(b, n0, tid, x0, nullptr, p.RH0 + b * 16384,
                       rh, h0, h0, u, rh, p.A, p.Wp[1], p.bias[1],
                       p.H0[c0 ^ 1] + b * 16384, nullptr, nullptr, nullptr, nullptr,
                       xsT, Hbuf, ctr, st);
    c0 ^= 1;
    dc_stage<64, 128, 0>(b, n0, tid, nullptr, p.H0[c0] + b * 16384, p.H1[c1] + b * 16384,
                         h1, h0, h1, u, rh, p.A, p.Wp[2], p.bias[2],
                         p.RH1 + b * 16384, nullptr, nullptr, nullptr, nullptr,
                         xsT, Hbuf, ctr, st);
    dc_stage<64, 128, 1>(b, n0, tid, nullptr, p.H0[c0] + b * 16384, p.RH1 + b * 16384,
                         rh, h0, h1, u, rh, p.A, p.Wp[3], p.bias[3],
                         p.H1[c1 ^ 1] + b * 16384, nullptr, nullptr, nullptr, nullptr,
                         xsT, Hbuf, ctr, st);
    c1 ^= 1;
  }

  // ---- decoder ----
  for (int t = 0; t < 12; ++t) {
    const float* xd = t ? (p.XD + b * 256) : nullptr;
    dc_stage<1, 96, 0>(b, n0, tid, xd, nullptr, p.H0[c0] + b * 16384,
                       h0, h0, h0, u, rh, p.A, p.Wp[4], p.bias[4],
                       p.RH0 + b * 16384, nullptr, nullptr, nullptr, nullptr,
                       xsT, Hbuf, ctr, st);
    dc_stage<1, 96, 1>(b, n0, tid, xd, nullptr, p.RH0 + b * 16384,
                       rh, h0, h0, u, rh, p.A, p.Wp[5], p.bias[5],
                       p.H0[c0 ^ 1] + b * 16384, nullptr, nullptr, nullptr, nullptr,
                       xsT, Hbuf, ctr, st);
    c0 ^= 1;
    dc_stage<64, 128, 0>(b, n0, tid, nullptr, p.H0[c0] + b * 16384, p.H1[c1] + b * 16384,
                         h1, h0, h1, u, rh, p.A, p.Wp[6], p.bias[6],
                         p.RH1 + b * 16384, nullptr, nullptr, nullptr, nullptr,
                         xsT, Hbuf, ctr, st);
    dc_stage<64, 128, 2>(b, n0, tid, nullptr, p.H0[c0] + b * 16384, p.RH1 + b * 16384,
                         rh, h0, h1, u, rh, p.A, p.Wp[7], p.bias[7],
                         p.H1[c1 ^ 1] + b * 16384, p.prW, p.prB,
                         p.out + t * 256, p.XD, xsT, Hbuf, ctr, st);
    c1 ^= 1;
  }
}

// ---------------- host ----------------
extern "C" void kernel_launch(void* const* d_in, const int* in_sizes, int n_in,
                              void* d_out, int out_size, void* d_ws, size_t ws_size,
                              hipStream_t stream)
{
  (void)in_sizes; (void)n_in; (void)out_size; (void)ws_size;
  KP p;
  p.enc_in = (const float*)d_in[0];
  p.sup0 = (const float*)d_in[2];
  p.sup1 = (const float*)d_in[3];
  p.Wsrc[0] = (const float*)d_in[4];  p.bias[0] = (const float*)d_in[5];
  p.Wsrc[1] = (const float*)d_in[6];  p.bias[1] = (const float*)d_in[7];
  p.Wsrc[2] = (const float*)d_in[8];  p.bias[2] = (const float*)d_in[9];
  p.Wsrc[3] = (const float*)d_in[10]; p.bias[3] = (const float*)d_in[11];
  p.Wsrc[4] = (const float*)d_in[12]; p.bias[4] = (const float*)d_in[13];
  p.Wsrc[5] = (const float*)d_in[14]; p.bias[5] = (const float*)d_in[15];
  p.Wsrc[6] = (const float*)d_in[16]; p.bias[6] = (const float*)d_in[17];
  p.Wsrc[7] = (const float*)d_in[18]; p.bias[7] = (const float*)d_in[19];
  p.prW = (const float*)d_in[20];
  p.prB = (const float*)d_in[21];
  p.out = (float*)d_out;

  char* ws = (char*)d_ws;
  size_t off = 0;
  auto carve = [&](size_t bytes) -> char* {
    char* qp = ws + off;
    off += (bytes + 255) & ~(size_t)255;
    return qp;
  };
  p.A = (unsigned short*)carve(4 * 65536 * 2);
  p.Wp[0] = (unsigned short*)carve(128 * 480 * 2);
  p.Wp[1] = (unsigned short*)carve(64 * 480 * 2);
  p.Wp[2] = (unsigned short*)carve(128 * 640 * 2);
  p.Wp[3] = (unsigned short*)carve(64 * 640 * 2);
  p.Wp[4] = (unsigned short*)carve(128 * 480 * 2);
  p.Wp[5] = (unsigned short*)carve(64 * 480 * 2);
  p.Wp[6] = (unsigned short*)carve(128 * 640 * 2);
  p.Wp[7] = (unsigned short*)carve(64 * 640 * 2);
  p.H0[0] = (unsigned short*)carve(64 * 64 * 256 * 2);
  p.H0[1] = (unsigned short*)carve(64 * 64 * 256 * 2);
  p.H1[0] = (unsigned short*)carve(64 * 64 * 256 * 2);
  p.H1[1] = (unsigned short*)carve(64 * 64 * 256 * 2);
  p.RH0 = (unsigned short*)carve(64 * 64 * 256 * 2);
  p.RH1 = (unsigned short*)carve(64 * 64 * 256 * 2);
  p.XD = (float*)carve(64 * 256 * 4);
  p.ctr = (unsigned*)carve(64 * 256);

  prep<<<dim3(512), dim3(256), 0, stream>>>(p);
  dcrnn_main<<<dim3(256), dim3(512), 0, stream>>>(p);
}